// Round 4
// baseline (1569.683 us; speedup 1.0000x reference)
//
#include <hip/hip_runtime.h>
#include <math.h>

#define TINYF 1.17549435e-38f
#define TINYD 1.1754943508222875e-38  // float32 tiny, exact

namespace {
constexpr int kB = 8, kD = 256, kC = 1024, kR = 64, kO = 256;
constexpr int kS = kB * kC;  // 8192 samples
// workspace byte offsets
constexpr size_t OFF_G1B  = 0;                                  // float [D][R] inv_s2
constexpr size_t OFF_G2B  = OFF_G1B + sizeof(float) * kD * kR;  // float [D][R] c*inv_s2
constexpr size_t OFF_G3B  = OFF_G2B + sizeof(float) * kD * kR;  // float [R]
constexpr size_t OFF_IMPB = OFF_G3B + sizeof(float) * kR + 32;  // double [R]
constexpr size_t OFF_NTB  = OFF_IMPB + sizeof(double) * kR;     // float [R][S]
}  // namespace

// numpy pairwise_sum order for n=64 f32 (8 strided accumulators + fixed tree).
__device__ __forceinline__ float np_sum64(const float* __restrict__ a) {
#pragma clang fp contract(off)
  float r0 = a[0], r1 = a[1], r2 = a[2], r3 = a[3];
  float r4 = a[4], r5 = a[5], r6 = a[6], r7 = a[7];
  for (int i = 8; i < 64; i += 8) {
    r0 += a[i + 0]; r1 += a[i + 1]; r2 += a[i + 2]; r3 += a[i + 3];
    r4 += a[i + 4]; r5 += a[i + 5]; r6 += a[i + 6]; r7 += a[i + 7];
  }
  return ((r0 + r1) + (r2 + r3)) + ((r4 + r5) + (r6 + r7));
}

// ------------------------------------------------------------- prep g1/g2 (f32)
__global__ __launch_bounds__(256) void prep_kernel(const float* __restrict__ center,
                                                   const float* __restrict__ sigma,
                                                   float* __restrict__ g1,
                                                   float* __restrict__ g2) {
#pragma clang fp contract(off)
  int r = blockIdx.x;   // 64
  int d = threadIdx.x;  // 256 == D
  float sg = sigma[r * kD + d] + TINYF;      // f32, like ref (sigma + TINY)
  float is2 = 1.0f / (sg * sg);              // f32 square, f32 divide
  float cn = center[r * kD + d];
  g1[(size_t)d * kR + r] = is2;
  g2[(size_t)d * kR + r] = cn * is2;         // f32 product, like ref center*inv_s2
}

// ---------------- g3[r] = np.sum(c*c*is2, axis=-1): numpy pairwise n=256 exact
__global__ __launch_bounds__(64) void g3_kernel(const float* __restrict__ center,
                                                const float* __restrict__ sigma,
                                                float* __restrict__ g3) {
#pragma clang fp contract(off)
  int r = threadIdx.x;
  const float* cp = center + (size_t)r * kD;
  const float* sp = sigma + (size_t)r * kD;
  float half[2];
  for (int blk = 0; blk < 2; ++blk) {  // pairwise(256) = pw(0..128) + pw(128..256)
    const float* c = cp + blk * 128;
    const float* s = sp + blk * 128;
    float rr[8];
    for (int j = 0; j < 8; ++j) {
      float sg = s[j] + TINYF;
      float is2 = 1.0f / (sg * sg);
      rr[j] = (c[j] * c[j]) * is2;
    }
    for (int i = 8; i < 128; i += 8)
      for (int j = 0; j < 8; ++j) {
        float sg = s[i + j] + TINYF;
        float is2 = 1.0f / (sg * sg);
        rr[j] = rr[j] + (c[i + j] * c[i + j]) * is2;
      }
    half[blk] = ((rr[0] + rr[1]) + (rr[2] + rr[3])) + ((rr[4] + rr[5]) + (rr[6] + rr[7]));
  }
  g3[r] = half[0] + half[1];
}

// ---- norm: numpy-f32-bit-replicated distances, softmax, top-p, renorm.
// einsum("bcd,rd->bcr") with non-contiguous xt (and order-'K' xt*xt) takes
// numpy einsum's generic-stride sum_of_products path: SEQUENTIAL single-
// accumulator f32 over d. One wave per 4 samples; lane = rule index r.
__global__ __launch_bounds__(256) void norm_kernel(const float* __restrict__ x,
                                                   const float* __restrict__ g1,
                                                   const float* __restrict__ g2,
                                                   const float* __restrict__ g3,
                                                   float* __restrict__ nt, float tauf) {
#pragma clang fp contract(off)
  __shared__ float buf[4][64];  // fire, then masked values
  __shared__ float nfb[4][64];  // f32 norm values
  __shared__ float sb[4][64];   // sorted-desc norm values
  __shared__ float bc[4];       // per-wave threshold broadcast
  int w = threadIdx.x >> 6;
  int lane = threadIdx.x & 63;
  int s0 = blockIdx.x * 16 + w * 4;  // 4 consecutive samples (same b: 16 | 1024)
  int b = s0 >> 10;
  int c0 = s0 & (kC - 1);
  const float* xb = x + (size_t)b * kD * kC + c0;
  // e1 = sum_d (x*x)*is2, e2 = sum_d x*(c*is2): sequential f32, separate mul/add
  float e1[4] = {0.f, 0.f, 0.f, 0.f}, e2[4] = {0.f, 0.f, 0.f, 0.f};
  for (int d = 0; d < kD; ++d) {
    float a1 = g1[(size_t)d * kR + lane];  // coalesced across lanes
    float a2 = g2[(size_t)d * kR + lane];
    float4 xv = *(const float4*)(xb + (size_t)d * kC);  // wave-uniform broadcast
    float xs[4] = {xv.x, xv.y, xv.z, xv.w};
    for (int q = 0; q < 4; ++q) {
      float xx = xs[q] * xs[q];            // f32 (ref: xt*xt elementwise temp)
      e1[q] = e1[q] + xx * a1;             // mul rounds, add rounds (no fma)
      e2[q] = e2[q] + xs[q] * a2;
    }
  }
  float g3v = g3[lane];
#pragma unroll 1
  for (int q = 0; q < 4; ++q) {
    float sqf = (e1[q] - 2.0f * e2[q]) + g3v;  // 2*e2 exact; ref assoc order
    float argf = sqf * -0.001953125f;          // exact (power-of-2 scale)
    float firef = (float)exp((double)argf) + TINYF;  // ~np.exp f32 (<=1-2 ulp)
    buf[w][lane] = firef;
    __syncthreads();
    float ssum = np_sum64(buf[w]);          // numpy pairwise-64, f32
    float normf = firef / (ssum + TINYF);   // f32 division
    nfb[w][lane] = normf;
    __syncthreads();
    // stable descending rank (ties by lane index; tied values identical)
    int rank = 0;
    for (int j = 0; j < 64; ++j) {
      float vj = nfb[w][j];
      rank += (vj > normf) || (vj == normf && j < lane);
    }
    sb[w][rank] = normf;
    __syncthreads();
    if (lane == 0) {  // literal np: sequential f32 cumsum, err, first-argmin
      float cs = 0.f, beste = 1e30f;
      int bidx = 0;
      for (int i = 0; i < 64; ++i) {
        cs = cs + sb[w][i];
        float e = cs - tauf;
        if (e < 0.f) e = 1.0f;
        if (e < beste) { beste = e; bidx = i; }
      }
      bc[w] = sb[w][bidx];
    }
    __syncthreads();
    float vals = bc[w];
    float masked = (normf >= vals) ? normf : 0.f;
    buf[w][lane] = masked;
    __syncthreads();
    float s2 = np_sum64(buf[w]);            // numpy pairwise-64, f32
    float ov = masked / (s2 + TINYF);       // f32 division
    nt[(size_t)lane * kS + s0 + q] = ov;    // transposed store for pred
    __syncthreads();  // buf reused next q
  }
}

// ------------------------------------------- imp: deterministic f64 per-rule sum
__global__ __launch_bounds__(256) void imp_kernel(const float* __restrict__ nt,
                                                  double* __restrict__ impd) {
  int r = blockIdx.x;
  int t = threadIdx.x;
  double a = 0.0;
  for (int s = t; s < kS; s += 256) a += (double)nt[(size_t)r * kS + s];
  __shared__ double red[256];
  red[t] = a;
  __syncthreads();
  for (int st = 128; st > 0; st >>= 1) {
    if (t < st) red[t] += red[t + st];
    __syncthreads();
  }
  if (t == 0) impd[r] = red[0];
}

// ---------------------------------------------------------------- loss (f64)
__global__ __launch_bounds__(64) void loss_kernel(const double* __restrict__ impd,
                                                  float* __restrict__ out) {
  int t = threadIdx.x;
  double v = impd[t];
  double sum = v;
#pragma unroll
  for (int off = 32; off; off >>= 1) sum += __shfl_xor(sum, off, 64);
  double mean = sum * (1.0 / 64.0);
  double dv = v - mean;
  double ss = dv * dv;
#pragma unroll
  for (int off = 32; off; off >>= 1) ss += __shfl_xor(ss, off, 64);
  double var = ss * (1.0 / 63.0);  // ddof=1
  if (t == 0) out[(size_t)kS * kO] = (float)(0.01 * (var / (mean * mean + 1e-20)));
}

// ------------------------------------- pred: fused cons-GEMM + norm contraction
// tile 64 samples x 128 outputs, 256 threads, per-thread 4s x 8o. f32.
__global__ __launch_bounds__(256) void pred_kernel(const float* __restrict__ x,
                                                   const float* __restrict__ Wm,
                                                   const float* __restrict__ bias,
                                                   const float* __restrict__ nt,
                                                   float* __restrict__ out) {
  __shared__ float a_lds[64][64];      // [k][s]
  __shared__ float w_lds[2][64][128];  // [buf][k][o]
  int t = threadIdx.x;
  int st = blockIdx.x & 127;
  int ot = blockIdx.x >> 7;
  int s0 = st * 64;
  int b = s0 >> 10;
  int c0 = s0 & (kC - 1);
  int o0 = ot * 128;
  int sg = (t & 15) * 4;  // this thread's 4 samples (contiguous)
  int og = (t >> 4) * 8;  // this thread's 8 outputs (contiguous)
  int lo = t >> 4;        // load row-group 0..15
  float acc[4][8] = {};
  const float* xb = x + (size_t)b * kD * kC;
  for (int chunk = 0; chunk < 4; ++chunk) {
    int k0 = chunk * 64;
    __syncthreads();  // previous chunk's readers done
#pragma unroll
    for (int i = 0; i < 4; ++i) {  // A chunk: a_lds[k][s] = x[b][k0+k][c0+s]
      int k = i * 16 + lo;
      *(float4*)&a_lds[k][sg] = *(const float4*)(xb + (size_t)(k0 + k) * kC + c0 + sg);
    }
#pragma unroll
    for (int i = 0; i < 8; ++i) {  // W tile r=0 (transposed into [k][o])
      int o = i * 16 + lo;
      float4 v = *(const float4*)(Wm + (size_t)(o0 + o) * kD + k0 + sg);
      w_lds[0][sg + 0][o] = v.x;
      w_lds[0][sg + 1][o] = v.y;
      w_lds[0][sg + 2][o] = v.z;
      w_lds[0][sg + 3][o] = v.w;
    }
    __syncthreads();
    for (int r = 0; r < 64; ++r) {
      float4 pre[8];
      if (r < 63) {  // prefetch next r's W tile to registers (hides L2 latency)
#pragma unroll
        for (int i = 0; i < 8; ++i) {
          int o = i * 16 + lo;
          pre[i] = *(const float4*)(Wm + (size_t)((r + 1) * kO + o0 + o) * kD + k0 + sg);
        }
      }
      float part[4][8] = {};
      const float(*wb)[128] = w_lds[r & 1];
#pragma unroll 4
      for (int k = 0; k < 64; ++k) {
        float4 a4 = *(const float4*)&a_lds[k][sg];
        float4 w0 = *(const float4*)&wb[k][og];
        float4 w1 = *(const float4*)&wb[k][og + 4];
        float av[4] = {a4.x, a4.y, a4.z, a4.w};
        float wv[8] = {w0.x, w0.y, w0.z, w0.w, w1.x, w1.y, w1.z, w1.w};
#pragma unroll
        for (int i = 0; i < 4; ++i)
#pragma unroll
          for (int j = 0; j < 8; ++j) part[i][j] = fmaf(av[i], wv[j], part[i][j]);
      }
      float4 nv = *(const float4*)(nt + (size_t)r * kS + s0 + sg);
      float nva[4] = {nv.x, nv.y, nv.z, nv.w};
      if (chunk == 3) {  // bias folded in exactly once (last chunk)
        float4 b0 = *(const float4*)(bias + r * kO + o0 + og);
        float4 b1 = *(const float4*)(bias + r * kO + o0 + og + 4);
        float bj[8] = {b0.x, b0.y, b0.z, b0.w, b1.x, b1.y, b1.z, b1.w};
#pragma unroll
        for (int i = 0; i < 4; ++i)
#pragma unroll
          for (int j = 0; j < 8; ++j)
            acc[i][j] = fmaf(nva[i], part[i][j] + bj[j], acc[i][j]);
      } else {
#pragma unroll
        for (int i = 0; i < 4; ++i)
#pragma unroll
          for (int j = 0; j < 8; ++j) acc[i][j] = fmaf(nva[i], part[i][j], acc[i][j]);
      }
      if (r < 63) {  // stage prefetched W into the other buffer
        float(*wn)[128] = w_lds[(r + 1) & 1];
#pragma unroll
        for (int i = 0; i < 8; ++i) {
          int o = i * 16 + lo;
          wn[sg + 0][o] = pre[i].x;
          wn[sg + 1][o] = pre[i].y;
          wn[sg + 2][o] = pre[i].z;
          wn[sg + 3][o] = pre[i].w;
        }
      }
      __syncthreads();
    }
  }
  // out is (B, O, C): out[b][o][c]
  size_t ob = (size_t)b * kO * kC + (size_t)o0 * kC + c0;
#pragma unroll
  for (int j = 0; j < 8; ++j) {
    float4 v = {acc[0][j], acc[1][j], acc[2][j], acc[3][j]};
    *(float4*)(out + ob + (size_t)(og + j) * kC + sg) = v;
  }
}

extern "C" void kernel_launch(void* const* d_in, const int* in_sizes, int n_in,
                              void* d_out, int out_size, void* d_ws, size_t ws_size,
                              hipStream_t stream) {
  const float* x = (const float*)d_in[0];
  const float* center = (const float*)d_in[1];
  const float* sigma = (const float*)d_in[2];
  const float* Wm = (const float*)d_in[3];
  const float* bias = (const float*)d_in[4];
  float* out = (float*)d_out;
  char* wsb = (char*)d_ws;
  float* g1 = (float*)(wsb + OFF_G1B);
  float* g2 = (float*)(wsb + OFF_G2B);
  float* g3 = (float*)(wsb + OFF_G3B);
  double* impd = (double*)(wsb + OFF_IMPB);
  float* nt = (float*)(wsb + OFF_NTB);
  // tau computed in f64 (python scalar math); ref's f32 array op casts to f32
  double tau = 0.9 * pow(1.0 / (64.0 + TINYD), 1.0 / 256.0);
  float tauf = (float)tau;
  prep_kernel<<<kR, 256, 0, stream>>>(center, sigma, g1, g2);
  g3_kernel<<<1, 64, 0, stream>>>(center, sigma, g3);
  norm_kernel<<<kS / 16, 256, 0, stream>>>(x, g1, g2, g3, nt, tauf);
  imp_kernel<<<kR, 256, 0, stream>>>(nt, impd);
  pred_kernel<<<256, 256, 0, stream>>>(x, Wm, bias, nt, out);
  loss_kernel<<<1, 64, 0, stream>>>(impd, out);
}

// Round 5
// 303.961 us; speedup vs baseline: 5.1641x; 5.1641x over previous
//
#include <hip/hip_runtime.h>
#include <math.h>

#define TINYF 1.17549435e-38f
#define TINYD 1.1754943508222875e-38  // float32 tiny, exact

namespace {
constexpr int kB = 8, kD = 256, kC = 1024, kR = 64, kO = 256;
constexpr int kS = kB * kC;  // 8192 samples
// workspace byte offsets
constexpr size_t OFF_G1B  = 0;        // float [D][R] inv_s2
constexpr size_t OFF_G2B  = 65536;    // float [D][R] c*inv_s2
constexpr size_t OFF_G3B  = 131072;   // float [R]
constexpr size_t OFF_IMPB = 131584;   // double [R]
constexpr size_t OFF_NTB  = 132096;   // float [R][S]  (2 MB)
constexpr size_t OFF_WBB  = OFF_NTB + (size_t)kR * kS * 4;        // bf16 W copy
constexpr size_t WS_NEED  = OFF_WBB + (size_t)kR * kO * kD * 2;   // ~10.6 MB
}  // namespace

typedef float f32x4 __attribute__((ext_vector_type(4)));
typedef short short8 __attribute__((ext_vector_type(8)));

__device__ __forceinline__ short f2bf(float f) {  // f32 -> bf16 bits, RNE
  unsigned u = __builtin_bit_cast(unsigned, f);
  unsigned r = ((u >> 16) & 1u) + 0x7fffu;
  return (short)((u + r) >> 16);
}
__device__ __forceinline__ unsigned pk(short a, short b) {
  return (unsigned)(unsigned short)a | ((unsigned)(unsigned short)b << 16);
}

// numpy pairwise_sum order for n=64 f32 (8 strided accumulators + fixed tree).
__device__ __forceinline__ float np_sum64(const float* __restrict__ a) {
#pragma clang fp contract(off)
  float r0 = a[0], r1 = a[1], r2 = a[2], r3 = a[3];
  float r4 = a[4], r5 = a[5], r6 = a[6], r7 = a[7];
  for (int i = 8; i < 64; i += 8) {
    r0 += a[i + 0]; r1 += a[i + 1]; r2 += a[i + 2]; r3 += a[i + 3];
    r4 += a[i + 4]; r5 += a[i + 5]; r6 += a[i + 6]; r7 += a[i + 7];
  }
  return ((r0 + r1) + (r2 + r3)) + ((r4 + r5) + (r6 + r7));
}

// ------------------------------------------------------------- prep g1/g2 (f32)
__global__ __launch_bounds__(256) void prep_kernel(const float* __restrict__ center,
                                                   const float* __restrict__ sigma,
                                                   float* __restrict__ g1,
                                                   float* __restrict__ g2) {
#pragma clang fp contract(off)
  int r = blockIdx.x;
  int d = threadIdx.x;
  float sg = sigma[r * kD + d] + TINYF;
  float is2 = 1.0f / (sg * sg);
  float cn = center[r * kD + d];
  g1[(size_t)d * kR + r] = is2;
  g2[(size_t)d * kR + r] = cn * is2;
}

// ---------------- g3[r] = np.sum(c*c*is2, axis=-1): numpy pairwise n=256 exact
__global__ __launch_bounds__(64) void g3_kernel(const float* __restrict__ center,
                                                const float* __restrict__ sigma,
                                                float* __restrict__ g3) {
#pragma clang fp contract(off)
  int r = threadIdx.x;
  const float* cp = center + (size_t)r * kD;
  const float* sp = sigma + (size_t)r * kD;
  float half[2];
  for (int blk = 0; blk < 2; ++blk) {
    const float* c = cp + blk * 128;
    const float* s = sp + blk * 128;
    float rr[8];
    for (int j = 0; j < 8; ++j) {
      float sg = s[j] + TINYF;
      float is2 = 1.0f / (sg * sg);
      rr[j] = (c[j] * c[j]) * is2;
    }
    for (int i = 8; i < 128; i += 8)
      for (int j = 0; j < 8; ++j) {
        float sg = s[i + j] + TINYF;
        float is2 = 1.0f / (sg * sg);
        rr[j] = rr[j] + (c[i + j] * c[i + j]) * is2;
      }
    half[blk] = ((rr[0] + rr[1]) + (rr[2] + rr[3])) + ((rr[4] + rr[5]) + (rr[6] + rr[7]));
  }
  g3[r] = half[0] + half[1];
}

// ---- norm: numpy-f32-bit-replicated distances, softmax, top-p, renorm (PASSED r4)
__global__ __launch_bounds__(256) void norm_kernel(const float* __restrict__ x,
                                                   const float* __restrict__ g1,
                                                   const float* __restrict__ g2,
                                                   const float* __restrict__ g3,
                                                   float* __restrict__ nt, float tauf) {
#pragma clang fp contract(off)
  __shared__ float buf[4][64];
  __shared__ float nfb[4][64];
  __shared__ float sb[4][64];
  __shared__ float bc[4];
  int w = threadIdx.x >> 6;
  int lane = threadIdx.x & 63;
  int s0 = blockIdx.x * 16 + w * 4;
  int b = s0 >> 10;
  int c0 = s0 & (kC - 1);
  const float* xb = x + (size_t)b * kD * kC + c0;
  float e1[4] = {0.f, 0.f, 0.f, 0.f}, e2[4] = {0.f, 0.f, 0.f, 0.f};
  for (int d = 0; d < kD; ++d) {
    float a1 = g1[(size_t)d * kR + lane];
    float a2 = g2[(size_t)d * kR + lane];
    float4 xv = *(const float4*)(xb + (size_t)d * kC);
    float xs[4] = {xv.x, xv.y, xv.z, xv.w};
    for (int q = 0; q < 4; ++q) {
      float xx = xs[q] * xs[q];
      e1[q] = e1[q] + xx * a1;
      e2[q] = e2[q] + xs[q] * a2;
    }
  }
  float g3v = g3[lane];
#pragma unroll 1
  for (int q = 0; q < 4; ++q) {
    float sqf = (e1[q] - 2.0f * e2[q]) + g3v;
    float argf = sqf * -0.001953125f;
    float firef = (float)exp((double)argf) + TINYF;
    buf[w][lane] = firef;
    __syncthreads();
    float ssum = np_sum64(buf[w]);
    float normf = firef / (ssum + TINYF);
    nfb[w][lane] = normf;
    __syncthreads();
    int rank = 0;
    for (int j = 0; j < 64; ++j) {
      float vj = nfb[w][j];
      rank += (vj > normf) || (vj == normf && j < lane);
    }
    sb[w][rank] = normf;
    __syncthreads();
    if (lane == 0) {
      float cs = 0.f, beste = 1e30f;
      int bidx = 0;
      for (int i = 0; i < 64; ++i) {
        cs = cs + sb[w][i];
        float e = cs - tauf;
        if (e < 0.f) e = 1.0f;
        if (e < beste) { beste = e; bidx = i; }
      }
      bc[w] = sb[w][bidx];
    }
    __syncthreads();
    float vals = bc[w];
    float masked = (normf >= vals) ? normf : 0.f;
    buf[w][lane] = masked;
    __syncthreads();
    float s2 = np_sum64(buf[w]);
    float ov = masked / (s2 + TINYF);
    nt[(size_t)lane * kS + s0 + q] = ov;
    __syncthreads();
  }
}

// ------------------------------------------- imp: deterministic f64 per-rule sum
__global__ __launch_bounds__(256) void imp_kernel(const float* __restrict__ nt,
                                                  double* __restrict__ impd) {
  int r = blockIdx.x;
  int t = threadIdx.x;
  double a = 0.0;
  for (int s = t; s < kS; s += 256) a += (double)nt[(size_t)r * kS + s];
  __shared__ double red[256];
  red[t] = a;
  __syncthreads();
  for (int st = 128; st > 0; st >>= 1) {
    if (t < st) red[t] += red[t + st];
    __syncthreads();
  }
  if (t == 0) impd[r] = red[0];
}

// ---------------------------------------------------------------- loss (f64)
__global__ __launch_bounds__(64) void loss_kernel(const double* __restrict__ impd,
                                                  float* __restrict__ out) {
  int t = threadIdx.x;
  double v = impd[t];
  double sum = v;
#pragma unroll
  for (int off = 32; off; off >>= 1) sum += __shfl_xor(sum, off, 64);
  double mean = sum * (1.0 / 64.0);
  double dv = v - mean;
  double ss = dv * dv;
#pragma unroll
  for (int off = 32; off; off >>= 1) ss += __shfl_xor(ss, off, 64);
  double var = ss * (1.0 / 63.0);
  if (t == 0) out[(size_t)kS * kO] = (float)(0.01 * (var / (mean * mean + 1e-20)));
}

// ----------------------------------------------- W f32 -> bf16 copy (preconv)
__global__ __launch_bounds__(256) void wcvt_kernel(const float* __restrict__ Wm,
                                                   short* __restrict__ Wb) {
  size_t i = ((size_t)blockIdx.x * 256 + threadIdx.x) * 4;
  float4 v = *(const float4*)(Wm + i);
  uint2 p;
  p.x = pk(f2bf(v.x), f2bf(v.y));
  p.y = pk(f2bf(v.z), f2bf(v.w));
  *(uint2*)(Wb + i) = p;
}

// ------------------- pred: bf16-MFMA cons GEMM + f32 norm contraction + bias
// grid 256 (XCD-swizzled): block = 128 s x 64 o; 4 waves of 32s x 64o each.
// K-loop: 128 iters (r 0..63 inner, half h 0..1 outer); W bf16 staged
// [64o][128k] XOR-swizzled, double-buffered, global_load_lds w/ counted vmcnt.
// x fragments live in registers per half (one-time loads). bias slice in LDS.
template <int PRECONV>
__global__ __launch_bounds__(256, 1) void pred_kernel(
    const float* __restrict__ x, const float* __restrict__ Wm,
    const short* __restrict__ Wb, const float* __restrict__ bias,
    const float* __restrict__ nt, float* __restrict__ out) {
  __shared__ __align__(16) short w_smem[2][64 * 128];  // 2 x 16 KB
  __shared__ __align__(16) float bias_smem[64 * 64];   // 16 KB
  int tid = threadIdx.x;
  int w = tid >> 6, l = tid & 63;
  // swizzled block mapping: o-tile pinned per XCD-pair (W slice 2MB -> L2-fit)
  int bid = blockIdx.x;
  int o_t = (bid & 7) >> 1;
  int s_t = ((bid >> 3) << 1) | (bid & 1);
  int o0 = o_t * 64;
  int b = s_t >> 3;
  int c0 = (s_t & 7) * 128;
  int cbase = c0 + w * 32;
  const float* xb = x + (size_t)b * kD * kC + cbase;  // + f*16 + (l&15) per frag
  int sb_norm = s_t * 128 + w * 32 + ((l >> 4) << 2);

  // ---- prologue: bias slice -> LDS
  for (int i = tid; i < 4096; i += 256) {
    int rr = i >> 6, ol = i & 63;
    bias_smem[i] = bias[rr * 256 + o0 + ol];
  }
  // ---- x fragments for half 0 (registers)
  short8 a[2][4];
#pragma unroll
  for (int f = 0; f < 2; ++f)
#pragma unroll
    for (int kk = 0; kk < 4; ++kk) {
      const float* xp = xb + (size_t)(kk * 32 + ((l >> 4) << 3)) * kC + f * 16 + (l & 15);
      short8 v;
#pragma unroll
      for (int j = 0; j < 8; ++j) v[j] = f2bf(xp[(size_t)j * kC]);
      a[f][kk] = v;
    }
  // ---- norm for t=0 (r=0)
  f32x4 nrm_c[2], nrm_n[2];
  nrm_c[0] = *(const f32x4*)(nt + sb_norm);
  nrm_c[1] = *(const f32x4*)(nt + sb_norm + 16);

  float4 wreg[8];  // fallback staging regs
  // ---- stage tile 0 (h=0, r=0) into buf 0
  if constexpr (PRECONV) {
#pragma unroll
    for (int i = 0; i < 4; ++i) {
      int seg = w * 4 + i;
      int o_l = seg * 4 + (l >> 4);
      int blk = (l & 15) ^ (o_l & 7);
      const char* src = (const char*)Wb + ((size_t)(o0 + o_l)) * 512 + blk * 16;
      __builtin_amdgcn_global_load_lds(
          (const __attribute__((address_space(1))) void*)src,
          (__attribute__((address_space(3))) void*)((char*)&w_smem[0][0] + seg * 1024),
          16, 0, 0);
    }
    asm volatile("s_waitcnt vmcnt(0)" ::: "memory");
  } else {
    int o = tid >> 2, k0 = (tid & 3) * 32;
    const float* src = Wm + ((size_t)(o0 + o)) * kD + k0;
    char* base = (char*)&w_smem[0][0] + o * 256;
#pragma unroll
    for (int i = 0; i < 8; ++i) {
      float4 v = *(const float4*)(src + i * 4);
      uint2 p;
      p.x = pk(f2bf(v.x), f2bf(v.y));
      p.y = pk(f2bf(v.z), f2bf(v.w));
      int kb = (k0 + i * 4) * 2;
      *(uint2*)(base + (kb ^ ((o & 7) << 4))) = p;
    }
  }
  __syncthreads();

  f32x4 acc[2][4];
#pragma unroll
  for (int f = 0; f < 2; ++f)
#pragma unroll
    for (int q = 0; q < 4; ++q) acc[f][q] = (f32x4){0.f, 0.f, 0.f, 0.f};

  int cur = 0;
  for (int t = 0; t < 128; ++t) {
    int h = t >> 6, r = t & 63;
    __syncthreads();  // A: all waves done reading buf cur^1 (prev iter)
    if constexpr (PRECONV) {
      if (t < 127) {
        int tn = t + 1, hn = tn >> 6, rn = tn & 63;
        char* dst = (char*)&w_smem[cur ^ 1][0];
#pragma unroll
        for (int i = 0; i < 4; ++i) {
          int seg = w * 4 + i;
          int o_l = seg * 4 + (l >> 4);
          int blk = (l & 15) ^ (o_l & 7);
          const char* src = (const char*)Wb + ((size_t)(rn * 256 + o0 + o_l)) * 512 +
                            hn * 256 + blk * 16;
          __builtin_amdgcn_global_load_lds(
              (const __attribute__((address_space(1))) void*)src,
              (__attribute__((address_space(3))) void*)(dst + seg * 1024), 16, 0, 0);
        }
        // in-flight (issue order): stage(t)[4], norm(t)[2], stage(t+1)[4]
        asm volatile("s_waitcnt vmcnt(6)" ::: "memory");  // drains stage(t)
      } else {
        asm volatile("s_waitcnt vmcnt(2)" ::: "memory");
      }
      __syncthreads();  // B: buf 'cur' fully staged for all waves
    } else {
      if (t < 127) {  // issue f32 W loads early; latency hides under compute
        int tn = t + 1, hn = tn >> 6, rn = tn & 63;
        int o = tid >> 2, k0 = (tid & 3) * 32;
        const float* src = Wm + ((size_t)(rn * 256 + o0 + o)) * kD + hn * 128 + k0;
#pragma unroll
        for (int i = 0; i < 8; ++i) wreg[i] = *(const float4*)(src + i * 4);
      }
    }
    // ---- half-1 x fragments (once)
    if (t == 64) {
#pragma unroll
      for (int f = 0; f < 2; ++f)
#pragma unroll
        for (int kk = 0; kk < 4; ++kk) {
          const float* xp = xb + (size_t)(128 + kk * 32 + ((l >> 4) << 3)) * kC +
                            f * 16 + (l & 15);
          short8 v;
#pragma unroll
          for (int j = 0; j < 8; ++j) v[j] = f2bf(xp[(size_t)j * kC]);
          a[f][kk] = v;
        }
    }
    // ---- compute: cons = x_half . W_r_half^T  (bf16 MFMA, f32 acc)
    f32x4 cons[2][4];
#pragma unroll
    for (int f = 0; f < 2; ++f)
#pragma unroll
      for (int q = 0; q < 4; ++q) cons[f][q] = (f32x4){0.f, 0.f, 0.f, 0.f};
    const char* wbuf = (const char*)&w_smem[cur][0];
#pragma unroll
    for (int kk = 0; kk < 4; ++kk) {
      short8 bfr[4];
#pragma unroll
      for (int q = 0; q < 4; ++q) {
        int orow = q * 16 + (l & 15);
        int kb = kk * 64 + ((l >> 4) << 4);
        bfr[q] = *(const short8*)(wbuf + orow * 256 + (kb ^ ((orow & 7) << 4)));
      }
#pragma unroll
      for (int f = 0; f < 2; ++f)
#pragma unroll
        for (int q = 0; q < 4; ++q)
          cons[f][q] =
              __builtin_amdgcn_mfma_f32_16x16x32_bf16(a[f][kk], bfr[q], cons[f][q], 0, 0, 0);
    }
    // ---- norm for next iter (L2, latency hidden by MFMA)
    if (t < 127) {
      int rn = (t + 1) & 63;
      nrm_n[0] = *(const f32x4*)(nt + (size_t)rn * kS + sb_norm);
      nrm_n[1] = *(const f32x4*)(nt + (size_t)rn * kS + sb_norm + 16);
    }
    if constexpr (!PRECONV) {
      __syncthreads();  // B: all waves done reading buf 'cur'
      if (t < 127) {
        int o = tid >> 2, k0 = (tid & 3) * 32;
        char* base = (char*)&w_smem[cur ^ 1][0] + o * 256;
#pragma unroll
        for (int i = 0; i < 8; ++i) {
          uint2 p;
          p.x = pk(f2bf(wreg[i].x), f2bf(wreg[i].y));
          p.y = pk(f2bf(wreg[i].z), f2bf(wreg[i].w));
          int kb = (k0 + i * 4) * 2;
          *(uint2*)(base + (kb ^ ((o & 7) << 4))) = p;
        }
      }
    }
    // ---- fold: acc += norm[s,r] * (cons + bias (at h==1 only, once per r))
#pragma unroll
    for (int f = 0; f < 2; ++f)
#pragma unroll
      for (int q = 0; q < 4; ++q) {
        float bv = 0.f;
        if (h == 1) bv = bias_smem[r * 64 + q * 16 + (l & 15)];
#pragma unroll
        for (int e = 0; e < 4; ++e)
          acc[f][q][e] += nrm_c[f][e] * (cons[f][q][e] + bv);
      }
    nrm_c[0] = nrm_n[0];
    nrm_c[1] = nrm_n[1];
    cur ^= 1;
  }
  // ---- store: out[b][o][c], C-frag col(o)=l&15, row(s/c)=4*(l>>4)+e
#pragma unroll
  for (int f = 0; f < 2; ++f)
#pragma unroll
    for (int q = 0; q < 4; ++q) {
      int o_abs = o0 + q * 16 + (l & 15);
      int c_abs = cbase + f * 16 + ((l >> 4) << 2);
      *(f32x4*)(out + (size_t)b * (kO * kC) + (size_t)o_abs * kC + c_abs) = acc[f][q];
    }
}

extern "C" void kernel_launch(void* const* d_in, const int* in_sizes, int n_in,
                              void* d_out, int out_size, void* d_ws, size_t ws_size,
                              hipStream_t stream) {
  const float* x = (const float*)d_in[0];
  const float* center = (const float*)d_in[1];
  const float* sigma = (const float*)d_in[2];
  const float* Wm = (const float*)d_in[3];
  const float* bias = (const float*)d_in[4];
  float* out = (float*)d_out;
  char* wsb = (char*)d_ws;
  float* g1 = (float*)(wsb + OFF_G1B);
  float* g2 = (float*)(wsb + OFF_G2B);
  float* g3 = (float*)(wsb + OFF_G3B);
  double* impd = (double*)(wsb + OFF_IMPB);
  float* nt = (float*)(wsb + OFF_NTB);
  short* Wb = (short*)(wsb + OFF_WBB);
  double tau = 0.9 * pow(1.0 / (64.0 + TINYD), 1.0 / 256.0);
  float tauf = (float)tau;
  bool preconv = (ws_size >= WS_NEED);
  prep_kernel<<<kR, 256, 0, stream>>>(center, sigma, g1, g2);
  g3_kernel<<<1, 64, 0, stream>>>(center, sigma, g3);
  norm_kernel<<<kS / 16, 256, 0, stream>>>(x, g1, g2, g3, nt, tauf);
  if (preconv) {
    wcvt_kernel<<<(kR * kO * kD) / 1024, 256, 0, stream>>>(Wm, Wb);
    pred_kernel<1><<<256, 256, 0, stream>>>(x, Wm, Wb, bias, nt, out);
  } else {
    pred_kernel<0><<<256, 256, 0, stream>>>(x, Wm, Wb, bias, nt, out);
  }
  imp_kernel<<<kR, 256, 0, stream>>>(nt, impd);
  loss_kernel<<<1, 64, 0, stream>>>(impd, out);
}

// Round 6
// 267.791 us; speedup vs baseline: 5.8616x; 1.1351x over previous
//
#include <hip/hip_runtime.h>
#include <math.h>

#define TINYF 1.17549435e-38f
#define TINYD 1.1754943508222875e-38  // float32 tiny, exact

namespace {
constexpr int kB = 8, kD = 256, kC = 1024, kR = 64, kO = 256;
constexpr int kS = kB * kC;  // 8192 samples
// workspace byte offsets
constexpr size_t OFF_G1B  = 0;        // float [D][R] inv_s2
constexpr size_t OFF_G2B  = 65536;    // float [D][R] c*inv_s2
constexpr size_t OFF_G3B  = 131072;   // float [R]
constexpr size_t OFF_IMPB = 131584;   // double [R]
constexpr size_t OFF_NTB  = 132096;   // float [R][S]  (2 MB)
constexpr size_t OFF_WBB  = OFF_NTB + (size_t)kR * kS * 4;        // bf16 W copy
constexpr size_t WS_NEED  = OFF_WBB + (size_t)kR * kO * kD * 2;   // ~10.6 MB
}  // namespace

typedef float f32x4 __attribute__((ext_vector_type(4)));
typedef short short8 __attribute__((ext_vector_type(8)));

__device__ __forceinline__ short f2bf(float f) {  // f32 -> bf16 bits, RNE
  unsigned u = __builtin_bit_cast(unsigned, f);
  unsigned r = ((u >> 16) & 1u) + 0x7fffu;
  return (short)((u + r) >> 16);
}
__device__ __forceinline__ unsigned pk(short a, short b) {
  return (unsigned)(unsigned short)a | ((unsigned)(unsigned short)b << 16);
}

// numpy pairwise_sum order for n=64 f32 (8 strided accumulators + fixed tree).
__device__ __forceinline__ float np_sum64(const float* __restrict__ a) {
#pragma clang fp contract(off)
  float r0 = a[0], r1 = a[1], r2 = a[2], r3 = a[3];
  float r4 = a[4], r5 = a[5], r6 = a[6], r7 = a[7];
  for (int i = 8; i < 64; i += 8) {
    r0 += a[i + 0]; r1 += a[i + 1]; r2 += a[i + 2]; r3 += a[i + 3];
    r4 += a[i + 4]; r5 += a[i + 5]; r6 += a[i + 6]; r7 += a[i + 7];
  }
  return ((r0 + r1) + (r2 + r3)) + ((r4 + r5) + (r6 + r7));
}

// ------------------------------------------------------------- prep g1/g2 (f32)
__global__ __launch_bounds__(256) void prep_kernel(const float* __restrict__ center,
                                                   const float* __restrict__ sigma,
                                                   float* __restrict__ g1,
                                                   float* __restrict__ g2) {
#pragma clang fp contract(off)
  int r = blockIdx.x;
  int d = threadIdx.x;
  float sg = sigma[r * kD + d] + TINYF;
  float is2 = 1.0f / (sg * sg);
  float cn = center[r * kD + d];
  g1[(size_t)d * kR + r] = is2;
  g2[(size_t)d * kR + r] = cn * is2;
}

// ---------------- g3[r] = np.sum(c*c*is2, axis=-1): numpy pairwise n=256 exact
__global__ __launch_bounds__(64) void g3_kernel(const float* __restrict__ center,
                                                const float* __restrict__ sigma,
                                                float* __restrict__ g3) {
#pragma clang fp contract(off)
  int r = threadIdx.x;
  const float* cp = center + (size_t)r * kD;
  const float* sp = sigma + (size_t)r * kD;
  float half[2];
  for (int blk = 0; blk < 2; ++blk) {
    const float* c = cp + blk * 128;
    const float* s = sp + blk * 128;
    float rr[8];
    for (int j = 0; j < 8; ++j) {
      float sg = s[j] + TINYF;
      float is2 = 1.0f / (sg * sg);
      rr[j] = (c[j] * c[j]) * is2;
    }
    for (int i = 8; i < 128; i += 8)
      for (int j = 0; j < 8; ++j) {
        float sg = s[i + j] + TINYF;
        float is2 = 1.0f / (sg * sg);
        rr[j] = rr[j] + (c[i + j] * c[i + j]) * is2;
      }
    half[blk] = ((rr[0] + rr[1]) + (rr[2] + rr[3])) + ((rr[4] + rr[5]) + (rr[6] + rr[7]));
  }
  g3[r] = half[0] + half[1];
}

// ---- norm: numpy-f32-bit-replicated distances, softmax, top-p, renorm (PASSED r4)
__global__ __launch_bounds__(256) void norm_kernel(const float* __restrict__ x,
                                                   const float* __restrict__ g1,
                                                   const float* __restrict__ g2,
                                                   const float* __restrict__ g3,
                                                   float* __restrict__ nt, float tauf) {
#pragma clang fp contract(off)
  __shared__ float buf[4][64];
  __shared__ float nfb[4][64];
  __shared__ float sb[4][64];
  __shared__ float bc[4];
  int w = threadIdx.x >> 6;
  int lane = threadIdx.x & 63;
  int s0 = blockIdx.x * 16 + w * 4;
  int b = s0 >> 10;
  int c0 = s0 & (kC - 1);
  const float* xb = x + (size_t)b * kD * kC + c0;
  float e1[4] = {0.f, 0.f, 0.f, 0.f}, e2[4] = {0.f, 0.f, 0.f, 0.f};
  for (int d = 0; d < kD; ++d) {
    float a1 = g1[(size_t)d * kR + lane];
    float a2 = g2[(size_t)d * kR + lane];
    float4 xv = *(const float4*)(xb + (size_t)d * kC);
    float xs[4] = {xv.x, xv.y, xv.z, xv.w};
    for (int q = 0; q < 4; ++q) {
      float xx = xs[q] * xs[q];
      e1[q] = e1[q] + xx * a1;
      e2[q] = e2[q] + xs[q] * a2;
    }
  }
  float g3v = g3[lane];
#pragma unroll 1
  for (int q = 0; q < 4; ++q) {
    float sqf = (e1[q] - 2.0f * e2[q]) + g3v;
    float argf = sqf * -0.001953125f;
    float firef = (float)exp((double)argf) + TINYF;
    buf[w][lane] = firef;
    __syncthreads();
    float ssum = np_sum64(buf[w]);
    float normf = firef / (ssum + TINYF);
    nfb[w][lane] = normf;
    __syncthreads();
    int rank = 0;
    for (int j = 0; j < 64; ++j) {
      float vj = nfb[w][j];
      rank += (vj > normf) || (vj == normf && j < lane);
    }
    sb[w][rank] = normf;
    __syncthreads();
    if (lane == 0) {
      float cs = 0.f, beste = 1e30f;
      int bidx = 0;
      for (int i = 0; i < 64; ++i) {
        cs = cs + sb[w][i];
        float e = cs - tauf;
        if (e < 0.f) e = 1.0f;
        if (e < beste) { beste = e; bidx = i; }
      }
      bc[w] = sb[w][bidx];
    }
    __syncthreads();
    float vals = bc[w];
    float masked = (normf >= vals) ? normf : 0.f;
    buf[w][lane] = masked;
    __syncthreads();
    float s2 = np_sum64(buf[w]);
    float ov = masked / (s2 + TINYF);
    nt[(size_t)lane * kS + s0 + q] = ov;
    __syncthreads();
  }
}

// ------------------------------------------- imp: deterministic f64 per-rule sum
__global__ __launch_bounds__(256) void imp_kernel(const float* __restrict__ nt,
                                                  double* __restrict__ impd) {
  int r = blockIdx.x;
  int t = threadIdx.x;
  double a = 0.0;
  for (int s = t; s < kS; s += 256) a += (double)nt[(size_t)r * kS + s];
  __shared__ double red[256];
  red[t] = a;
  __syncthreads();
  for (int st = 128; st > 0; st >>= 1) {
    if (t < st) red[t] += red[t + st];
    __syncthreads();
  }
  if (t == 0) impd[r] = red[0];
}

// ---------------------------------------------------------------- loss (f64)
__global__ __launch_bounds__(64) void loss_kernel(const double* __restrict__ impd,
                                                  float* __restrict__ out) {
  int t = threadIdx.x;
  double v = impd[t];
  double sum = v;
#pragma unroll
  for (int off = 32; off; off >>= 1) sum += __shfl_xor(sum, off, 64);
  double mean = sum * (1.0 / 64.0);
  double dv = v - mean;
  double ss = dv * dv;
#pragma unroll
  for (int off = 32; off; off >>= 1) ss += __shfl_xor(ss, off, 64);
  double var = ss * (1.0 / 63.0);
  if (t == 0) out[(size_t)kS * kO] = (float)(0.01 * (var / (mean * mean + 1e-20)));
}

// ----------------------------------------------- W f32 -> bf16 copy (preconv)
__global__ __launch_bounds__(256) void wcvt_kernel(const float* __restrict__ Wm,
                                                   short* __restrict__ Wb) {
  size_t i = ((size_t)blockIdx.x * 256 + threadIdx.x) * 4;
  float4 v = *(const float4*)(Wm + i);
  uint2 p;
  p.x = pk(f2bf(v.x), f2bf(v.y));
  p.y = pk(f2bf(v.z), f2bf(v.w));
  *(uint2*)(Wb + i) = p;
}

// ------------------- pred: bf16-MFMA cons GEMM + f32 norm contraction + bias
// grid 512: o_t = bid&7 (pinned per XCD, 1MB W slice L2-resident),
// s_t = bid>>3. Block = 128s x 32o, 4 waves of 32s x 32o; 2 blocks/CU.
// K-loop: 128 iters (r inner, half h outer). W bf16 [32o][128k] XOR-swizzled,
// double-buffered via global_load_lds; RAW s_barrier + manual counted vmcnt
// (no __syncthreads in the loop -> no compiler vmcnt(0) drain).
template <int PRECONV>
__global__ __launch_bounds__(256, 2) void pred_kernel(
    const float* __restrict__ x, const float* __restrict__ Wm,
    const short* __restrict__ Wb, const float* __restrict__ bias,
    const float* __restrict__ nt, float* __restrict__ out) {
  __shared__ __align__(16) short w_smem[2][32 * 128];  // 2 x 8 KB
  __shared__ __align__(16) float bias_smem[64 * 32];   // 8 KB
  int tid = threadIdx.x;
  int w = tid >> 6, l = tid & 63;
  int bid = blockIdx.x;
  int o_t = bid & 7;        // 8 o-tiles <-> 8 XCDs (round-robin dispatch)
  int s_t = bid >> 3;       // 64 s-tiles of 128 samples
  int o0 = o_t * 32;
  int b = s_t >> 3;
  int c0 = (s_t & 7) * 128;
  int cbase = c0 + w * 32;
  const float* xb = x + (size_t)b * kD * kC + cbase;
  int sb_norm = s_t * 128 + w * 32 + ((l >> 4) << 2);

  // ---- prologue: bias slice -> LDS  (bias_smem[r][o_local], 64x32)
  for (int i = tid; i < 2048; i += 256)
    bias_smem[i] = bias[(i >> 5) * 256 + o0 + (i & 31)];
  // ---- x fragments for half 0 (registers)
  short8 a[2][4];
#pragma unroll
  for (int f = 0; f < 2; ++f)
#pragma unroll
    for (int kk = 0; kk < 4; ++kk) {
      const float* xp = xb + (size_t)(kk * 32 + ((l >> 4) << 3)) * kC + f * 16 + (l & 15);
      short8 v;
#pragma unroll
      for (int j = 0; j < 8; ++j) v[j] = f2bf(xp[(size_t)j * kC]);
      a[f][kk] = v;
    }
  // ---- norm for t=0 (r=0)
  f32x4 nrm_c[2], nrm_n[2];
  nrm_c[0] = *(const f32x4*)(nt + sb_norm);
  nrm_c[1] = *(const f32x4*)(nt + sb_norm + 16);

  float4 wreg[4];  // fallback staging regs
  // ---- stage tile 0 (h=0, r=0) into buf 0: 8KB = 2 wave-issues x 1KB x 4 waves
  if constexpr (PRECONV) {
#pragma unroll
    for (int i = 0; i < 2; ++i) {
      int seg = w * 2 + i;                 // 0..7
      int o_l = seg * 4 + (l >> 4);        // 0..31
      int blk = (l & 15) ^ (o_l & 7);      // inverse-swizzled global source
      const char* src = (const char*)Wb + ((size_t)(o0 + o_l)) * 512 + blk * 16;
      __builtin_amdgcn_global_load_lds(
          (const __attribute__((address_space(1))) void*)src,
          (__attribute__((address_space(3))) void*)((char*)&w_smem[0][0] + seg * 1024),
          16, 0, 0);
    }
    asm volatile("s_waitcnt vmcnt(0)" ::: "memory");
  } else {
    int o = tid >> 3, ks = (tid & 7) * 16;
    const float* src = Wm + ((size_t)(o0 + o)) * kD + ks;
    char* base = (char*)&w_smem[0][0] + o * 256;
#pragma unroll
    for (int i = 0; i < 4; ++i) {
      float4 v = *(const float4*)(src + i * 4);
      uint2 p;
      p.x = pk(f2bf(v.x), f2bf(v.y));
      p.y = pk(f2bf(v.z), f2bf(v.w));
      int kb = (ks + i * 4) * 2;
      *(uint2*)(base + (kb ^ ((o & 7) << 4))) = p;
    }
  }
  __syncthreads();  // one-time; prologue drain is fine

  f32x4 acc[2][2];
#pragma unroll
  for (int f = 0; f < 2; ++f)
#pragma unroll
    for (int q = 0; q < 2; ++q) acc[f][q] = (f32x4){0.f, 0.f, 0.f, 0.f};

  int cur = 0;
  for (int t = 0; t < 128; ++t) {
    int h = t >> 6, r = t & 63;
    if constexpr (PRECONV) {
      // barrier A: all waves finished READING buf[cur^1] (last iter's ds_reads
      // retired before their MFMA use) -> safe to overwrite it.
      asm volatile("s_barrier" ::: "memory");
      if (t < 127) {
        int tn = t + 1, hn = tn >> 6, rn = tn & 63;
        char* dst = (char*)&w_smem[cur ^ 1][0];
#pragma unroll
        for (int i = 0; i < 2; ++i) {
          int seg = w * 2 + i;
          int o_l = seg * 4 + (l >> 4);
          int blk = (l & 15) ^ (o_l & 7);
          const char* src = (const char*)Wb + ((size_t)(rn * 256 + o0 + o_l)) * 512 +
                            hn * 256 + blk * 16;
          __builtin_amdgcn_global_load_lds(
              (const __attribute__((address_space(1))) void*)src,
              (__attribute__((address_space(3))) void*)(dst + seg * 1024), 16, 0, 0);
        }
        // outstanding (oldest first): stage(t)[2], norm[2], stage(t+1)[2]
        asm volatile("s_waitcnt vmcnt(4)" ::: "memory");  // drain stage(t) only
      } else {
        asm volatile("s_waitcnt vmcnt(2)" ::: "memory");  // drain stage(127)
      }
      // barrier B: every wave has drained ITS stage(t) -> buf[cur] fully valid
      asm volatile("s_barrier" ::: "memory");
    } else {
      __syncthreads();
      if (t < 127) {
        int tn = t + 1, hn = tn >> 6, rn = tn & 63;
        int o = tid >> 3, ks = (tid & 7) * 16;
        const float* src = Wm + ((size_t)(rn * 256 + o0 + o)) * kD + hn * 128 + ks;
#pragma unroll
        for (int i = 0; i < 4; ++i) wreg[i] = *(const float4*)(src + i * 4);
      }
    }
    // ---- half-1 x fragments (once)
    if (t == 64) {
#pragma unroll
      for (int f = 0; f < 2; ++f)
#pragma unroll
        for (int kk = 0; kk < 4; ++kk) {
          const float* xp = xb + (size_t)(128 + kk * 32 + ((l >> 4) << 3)) * kC +
                            f * 16 + (l & 15);
          short8 v;
#pragma unroll
          for (int j = 0; j < 8; ++j) v[j] = f2bf(xp[(size_t)j * kC]);
          a[f][kk] = v;
        }
    }
    // ---- compute: cons = x_half . W_r_half^T  (bf16 MFMA, f32 acc)
    f32x4 cons[2][2];
#pragma unroll
    for (int f = 0; f < 2; ++f)
#pragma unroll
      for (int q = 0; q < 2; ++q) cons[f][q] = (f32x4){0.f, 0.f, 0.f, 0.f};
    const char* wbuf = (const char*)&w_smem[cur][0];
#pragma unroll
    for (int kk = 0; kk < 4; ++kk) {
      short8 bfr[2];
#pragma unroll
      for (int q = 0; q < 2; ++q) {
        int orow = q * 16 + (l & 15);
        int kb = kk * 64 + ((l >> 4) << 4);
        bfr[q] = *(const short8*)(wbuf + orow * 256 + (kb ^ ((orow & 7) << 4)));
      }
#pragma unroll
      for (int f = 0; f < 2; ++f)
#pragma unroll
        for (int q = 0; q < 2; ++q)
          cons[f][q] =
              __builtin_amdgcn_mfma_f32_16x16x32_bf16(a[f][kk], bfr[q], cons[f][q], 0, 0, 0);
    }
    // ---- norm for next iter (stays in flight across the barrier; consumed
    // at next iter's fold via compiler-inserted counted vmcnt)
    if (t < 127) {
      int rn = (t + 1) & 63;
      nrm_n[0] = *(const f32x4*)(nt + (size_t)rn * kS + sb_norm);
      nrm_n[1] = *(const f32x4*)(nt + (size_t)rn * kS + sb_norm + 16);
    }
    if constexpr (!PRECONV) {
      __syncthreads();
      if (t < 127) {
        int o = tid >> 3, ks = (tid & 7) * 16;
        char* base = (char*)&w_smem[cur ^ 1][0] + o * 256;
#pragma unroll
        for (int i = 0; i < 4; ++i) {
          uint2 p;
          p.x = pk(f2bf(wreg[i].x), f2bf(wreg[i].y));
          p.y = pk(f2bf(wreg[i].z), f2bf(wreg[i].w));
          int kb = (ks + i * 4) * 2;
          *(uint2*)(base + (kb ^ ((o & 7) << 4))) = p;
        }
      }
    }
    // ---- fold: acc += norm[s,r] * (cons + bias (h==1 only, once per r))
#pragma unroll
    for (int f = 0; f < 2; ++f)
#pragma unroll
      for (int q = 0; q < 2; ++q) {
        float bv = 0.f;
        if (h == 1) bv = bias_smem[r * 32 + q * 16 + (l & 15)];
#pragma unroll
        for (int e = 0; e < 4; ++e)
          acc[f][q][e] += nrm_c[f][e] * (cons[f][q][e] + bv);
      }
    nrm_c[0] = nrm_n[0];
    nrm_c[1] = nrm_n[1];
    cur ^= 1;
  }
  // ---- store: out[b][o][c]
#pragma unroll
  for (int f = 0; f < 2; ++f)
#pragma unroll
    for (int q = 0; q < 2; ++q) {
      int o_abs = o0 + q * 16 + (l & 15);
      int c_abs = cbase + f * 16 + ((l >> 4) << 2);
      *(f32x4*)(out + (size_t)b * (kO * kC) + (size_t)o_abs * kC + c_abs) = acc[f][q];
    }
}

extern "C" void kernel_launch(void* const* d_in, const int* in_sizes, int n_in,
                              void* d_out, int out_size, void* d_ws, size_t ws_size,
                              hipStream_t stream) {
  const float* x = (const float*)d_in[0];
  const float* center = (const float*)d_in[1];
  const float* sigma = (const float*)d_in[2];
  const float* Wm = (const float*)d_in[3];
  const float* bias = (const float*)d_in[4];
  float* out = (float*)d_out;
  char* wsb = (char*)d_ws;
  float* g1 = (float*)(wsb + OFF_G1B);
  float* g2 = (float*)(wsb + OFF_G2B);
  float* g3 = (float*)(wsb + OFF_G3B);
  double* impd = (double*)(wsb + OFF_IMPB);
  float* nt = (float*)(wsb + OFF_NTB);
  short* Wb = (short*)(wsb + OFF_WBB);
  double tau = 0.9 * pow(1.0 / (64.0 + TINYD), 1.0 / 256.0);
  float tauf = (float)tau;
  bool preconv = (ws_size >= WS_NEED);
  prep_kernel<<<kR, 256, 0, stream>>>(center, sigma, g1, g2);
  g3_kernel<<<1, 64, 0, stream>>>(center, sigma, g3);
  norm_kernel<<<kS / 16, 256, 0, stream>>>(x, g1, g2, g3, nt, tauf);
  if (preconv) {
    wcvt_kernel<<<(kR * kO * kD) / 1024, 256, 0, stream>>>(Wm, Wb);
    pred_kernel<1><<<512, 256, 0, stream>>>(x, Wm, Wb, bias, nt, out);
  } else {
    pred_kernel<0><<<512, 256, 0, stream>>>(x, Wm, Wb, bias, nt, out);
  }
  imp_kernel<<<kR, 256, 0, stream>>>(nt, impd);
  loss_kernel<<<1, 64, 0, stream>>>(impd, out);
}